// Round 11
// baseline (44.111 us; speedup 1.0000x reference)
//
#include <hip/hip_runtime.h>
#include <hip/hip_bf16.h>

// out = conv9(in) @ M^T = (conv9(in @ M^T)),  M = Wout @ Win
// R11: conv fused into the GEMM's A-STAGING (register sliding window ->
// cvt_pk -> swizzled A-LDS). U intermediate eliminated; 2 launches.

typedef unsigned short u16;
typedef unsigned int u32;
typedef unsigned long long u64;
typedef __attribute__((ext_vector_type(8))) short bf16x8;
typedef __attribute__((ext_vector_type(8))) unsigned short u16x8;
typedef __attribute__((ext_vector_type(4))) float f32x4;
typedef __attribute__((ext_vector_type(2))) u32 u32x2;

typedef __attribute__((address_space(1))) const void* as1_cvp;
typedef __attribute__((address_space(3))) void* as3_vp;

#define EDIM 512
#define NROW 16384

__device__ __forceinline__ u16 f2b(float x) {
  union { float f; u32 u; } c; c.f = x;
  return (u16)((c.u + 0x7fffu + ((c.u >> 16) & 1u)) >> 16);  // RNE
}
__device__ __forceinline__ u32 cvtpk(float lo, float hi) {
  u32 r;
  asm("v_cvt_pk_bf16_f32 %0, %1, %2" : "=v"(r) : "v"(lo), "v"(hi));
  return r;
}
__device__ __forceinline__ void async_cp16(const void* g, void* l) {
  __builtin_amdgcn_global_load_lds((as1_cvp)(u64)g, (as3_vp)(u32)(u64)l, 16, 0, 0);
}

// ---------------------------------------------------------------------------
// Kernel 1: M[f,e] = sum_c Wout[f,c]*Win[c,e] (512^3), 64x64 tiles, BK=128,
// 4 steps, raw barriers + lgkm-only waits (R10's verified body).
// ---------------------------------------------------------------------------
__global__ __launch_bounds__(256) void gemm_m(const float* __restrict__ Wout,
                                              const float* __restrict__ Win,
                                              u16* __restrict__ Mm) {
  __shared__ u16 plds[17408];
  int t = threadIdx.x;
  u16* la = plds;          // A [f][c], stride 136
  u16* lbt = plds + 8704;  // B^T [e][c], stride 136
  int w = t >> 6, l = t & 63, lr = l & 15, lk = l >> 4;
  int f0 = ((int)blockIdx.x >> 3) * 64, e0 = ((int)blockIdx.x & 7) * 64;
  int arow = t >> 2, acol = (t & 3) * 32;
  int cq = t >> 3, eo = (t & 7) * 8;
  const float* pA = Wout + (u64)(f0 + arow) * EDIM + acol;
  const float* pB = Win + (u64)(4 * cq) * EDIM + e0 + eo;
  f32x4 a8[8], b8[8];
#pragma unroll
  for (int i = 0; i < 8; ++i) a8[i] = *(const f32x4*)(pA + i * 4);
#pragma unroll
  for (int r = 0; r < 4; ++r) {
    b8[r * 2 + 0] = *(const f32x4*)(pB + r * EDIM);
    b8[r * 2 + 1] = *(const f32x4*)(pB + r * EDIM + 4);
  }
  f32x4 acc[4] = {};
  for (int kt = 0; kt < 4; ++kt) {
#pragma unroll
    for (int i = 0; i < 4; ++i) {
      u16x8 o;
#pragma unroll
      for (int q = 0; q < 4; ++q) { o[q] = f2b(a8[2 * i][q]); o[4 + q] = f2b(a8[2 * i + 1][q]); }
      *(u16x8*)(la + arow * 136 + acol + i * 8) = o;
    }
#pragma unroll
    for (int j = 0; j < 8; ++j) {
      u32x2 p;
      p[0] = cvtpk(b8[0 + (j >> 2)][j & 3], b8[2 + (j >> 2)][j & 3]);
      p[1] = cvtpk(b8[4 + (j >> 2)][j & 3], b8[6 + (j >> 2)][j & 3]);
      *(u32x2*)(lbt + (eo + j) * 136 + 4 * cq) = p;
    }
    asm volatile("s_waitcnt lgkmcnt(0)" ::: "memory");
    __builtin_amdgcn_sched_barrier(0);
    __builtin_amdgcn_s_barrier();
    if (kt < 3) {
      pA += 128; pB += (u64)128 * EDIM;
#pragma unroll
      for (int i = 0; i < 8; ++i) a8[i] = *(const f32x4*)(pA + i * 4);
#pragma unroll
      for (int r = 0; r < 4; ++r) {
        b8[r * 2 + 0] = *(const f32x4*)(pB + r * EDIM);
        b8[r * 2 + 1] = *(const f32x4*)(pB + r * EDIM + 4);
      }
    }
#pragma unroll
    for (int kk = 0; kk < 128; kk += 32) {
      bf16x8 a = *(const bf16x8*)(la + (w * 16 + lr) * 136 + kk + lk * 8);
#pragma unroll
      for (int ni = 0; ni < 4; ++ni) {
        bf16x8 bb = *(const bf16x8*)(lbt + (ni * 16 + lr) * 136 + kk + lk * 8);
        acc[ni] = __builtin_amdgcn_mfma_f32_16x16x32_bf16(a, bb, acc[ni], 0, 0, 0);
      }
    }
    asm volatile("s_waitcnt lgkmcnt(0)" ::: "memory");
    __builtin_amdgcn_sched_barrier(0);
    __builtin_amdgcn_s_barrier();
  }
#pragma unroll
  for (int ni = 0; ni < 4; ++ni)
#pragma unroll
    for (int r = 0; r < 4; ++r)
      Mm[(u64)(f0 + w * 16 + lk * 4 + r) * EDIM + e0 + ni * 16 + lr] = f2b(acc[ni][r]);
}

// ---------------------------------------------------------------------------
// conv-to-LDS: thread owns 4 cols x 8 output rows; w[16] = fp32 window rows.
// Writes bf16 into XOR-swizzled A buffer. EDGE: batch-boundary tap masking.
// ---------------------------------------------------------------------------
template <bool EDGE>
__device__ __forceinline__ void conv_to_lds(u16* lds, int abase, const f32x4* w,
                                            int r0, int tg, int ct, const float* G) {
#pragma unroll
  for (int j = 0; j < 8; ++j) {
    f32x4 o = {};
    if (EDGE) {
      int rj = r0 + j, bat = rj >> 12;
#pragma unroll
      for (int k = 0; k < 9; ++k) {
        float g = (((rj + k - 4) >> 12) == bat) ? G[k < 4 ? 4 - k : k - 4] : 0.0f;
#pragma unroll
        for (int q = 0; q < 4; ++q) o[q] += g * w[j + k][q];
      }
    } else {
#pragma unroll
      for (int k = 0; k < 9; ++k) {
        float g = G[k < 4 ? 4 - k : k - 4];
#pragma unroll
        for (int q = 0; q < 4; ++q) o[q] += g * w[j + k][q];
      }
    }
    int row = tg * 8 + j;
    u32x2 p;
    p[0] = cvtpk(o[0], o[1]);
    p[1] = cvtpk(o[2], o[3]);
    *(u32x2*)(lds + abase + ((row * 64 + ct * 4) ^ ((row & 7) << 3))) = p;
  }
}

// ---------------------------------------------------------------------------
// Kernel 2: fused conv-staged GEMM. 128x128 tile, BK=64, 8 steps.
// A: fp32 window loads (depth-1 within step) -> conv -> swizzled A-LDS dbuf.
// B: global_load_lds (pre-swizzled source), dbuf. One barrier/step, counted
// vmcnt: [vmcnt(0); bar; W16; B4; MFMA; vmcnt(4); conv->A^1; lgkm(0)].
// 64KB LDS -> 2 blocks/CU; grid 512 = all resident. Output direct from acc.
// ---------------------------------------------------------------------------
template <bool EDGE>
__device__ __forceinline__ void fused_body(const float* __restrict__ in,
                                           const u16* __restrict__ Mm,
                                           float* __restrict__ out,
                                           u16* lds, int t, int m0, int n0) {
  const float G[5] = {0.39894228040143270f, 0.24197072451914337f,
                      0.053990966513188063f, 0.0044318484119380075f,
                      1.3383022576488537e-4f};
  int l = t & 63, lr = l & 15, lk = l >> 4;
  int wvi = t >> 6, wr = wvi >> 1, wc = wvi & 1;
  int ct = t & 15, tg = t >> 4;
  int r0 = m0 + tg * 8;

  u32 woff[16];
#pragma unroll
  for (int i = 0; i < 16; ++i) {
    int rr = r0 - 4 + i;
    rr = rr < 0 ? 0 : (rr > NROW - 1 ? NROW - 1 : rr);
    woff[i] = (u32)rr * EDIM + ct * 4;
  }
  int soct = (t & 7) ^ ((t >> 3) & 7);
  const u16* gB = Mm + (u64)(n0 + (t >> 3)) * EDIM + soct * 8;

  int ard[4], aswz[4], brd[4], bswz[4];
#pragma unroll
  for (int mi = 0; mi < 4; ++mi) {
    int rA = wr * 64 + mi * 16 + lr;
    ard[mi] = rA * 64; aswz[mi] = (rA & 7) << 3;
  }
#pragma unroll
  for (int ni = 0; ni < 4; ++ni) {
    int rB = wc * 64 + ni * 16 + lr;
    brd[ni] = rB * 64; bswz[ni] = (rB & 7) << 3;
  }

  f32x4 acc[4][4] = {};
  f32x4 w[16];

  // ---- prologue: W(0) -> conv -> Abuf0; issue B(0)
#pragma unroll
  for (int i = 0; i < 16; ++i) w[i] = *(const f32x4*)(in + woff[i]);
  conv_to_lds<EDGE>(lds, 0, w, r0, tg, ct, G);
#pragma unroll
  for (int i = 0; i < 4; ++i)
    async_cp16(gB + (u64)i * 32 * EDIM, lds + 16384 + t * 8 + i * 2048);
  asm volatile("s_waitcnt lgkmcnt(0)" ::: "memory");
  __builtin_amdgcn_sched_barrier(0);

#pragma unroll
  for (int kt = 0; kt < 8; ++kt) {
    asm volatile("s_waitcnt vmcnt(0)" ::: "memory");  // B(kt) + stragglers landed
    __builtin_amdgcn_sched_barrier(0);
    __builtin_amdgcn_s_barrier();  // A(kt), B(kt) visible; prev reads retired
    if (kt < 7) {  // W(kt+1): 16 fp32 window loads (oldest in queue)
#pragma unroll
      for (int i = 0; i < 16; ++i)
        w[i] = *(const f32x4*)(in + woff[i] + (kt + 1) * 64);
    }
    __builtin_amdgcn_sched_barrier(0);
    if (kt < 7) {  // B(kt+1) async -> buf^1 (stays in flight through conv)
#pragma unroll
      for (int i = 0; i < 4; ++i)
        async_cp16(gB + (kt + 1) * 64 + (u64)i * 32 * EDIM,
                   lds + 16384 + ((kt + 1) & 1) * 8192 + t * 8 + i * 2048);
    }
    __builtin_amdgcn_sched_barrier(0);
    int ab = (kt & 1) * 8192, bb = 16384 + (kt & 1) * 8192;
#pragma unroll
    for (int kk = 0; kk < 64; kk += 32) {
      bf16x8 af[4], bv[4];
#pragma unroll
      for (int mi = 0; mi < 4; ++mi)
        af[mi] = *(const bf16x8*)(lds + ab + ard[mi] + ((kk + lk * 8) ^ aswz[mi]));
#pragma unroll
      for (int ni = 0; ni < 4; ++ni)
        bv[ni] = *(const bf16x8*)(lds + bb + brd[ni] + ((kk + lk * 8) ^ bswz[ni]));
#pragma unroll
      for (int mi = 0; mi < 4; ++mi)
#pragma unroll
        for (int ni = 0; ni < 4; ++ni)
          acc[mi][ni] = __builtin_amdgcn_mfma_f32_16x16x32_bf16(af[mi], bv[ni],
                                                                acc[mi][ni], 0, 0, 0);
    }
    if (kt < 7) {
      asm volatile("s_waitcnt vmcnt(4)" ::: "memory");  // W16 retired; B4 in flight
      __builtin_amdgcn_sched_barrier(0);
      conv_to_lds<EDGE>(lds, ((kt + 1) & 1) * 8192, w, r0, tg, ct, G);
      asm volatile("s_waitcnt lgkmcnt(0)" ::: "memory");
      __builtin_amdgcn_sched_barrier(0);
    }
  }

  // ---- epilogue: direct fp32 stores from acc
#pragma unroll
  for (int mi = 0; mi < 4; ++mi)
#pragma unroll
    for (int ni = 0; ni < 4; ++ni)
#pragma unroll
      for (int rr = 0; rr < 4; ++rr)
        out[(u64)(m0 + wr * 64 + mi * 16 + lk * 4 + rr) * EDIM +
            n0 + wc * 64 + ni * 16 + lr] = acc[mi][ni][rr];
}

__global__ __launch_bounds__(256, 2) void fused_gc(const float* __restrict__ in,
                                                   const u16* __restrict__ Mm,
                                                   float* __restrict__ out) {
  __shared__ u16 lds[32768];  // A0@0 A1@8192 B0@16384 B1@24576 (u16 offsets)
  int t = threadIdx.x;
  int b = (int)blockIdx.x;
  int wg = (b & 7) * 64 + (b >> 3);  // 512 % 8 == 0: bijective XCD swizzle
  int m0 = (wg >> 2) * 128;
  int n0 = (wg & 3) * 128;
  bool edge = (((m0 - 4) >> 12) != ((m0 + 131) >> 12));
  if (edge)
    fused_body<true>(in, Mm, out, lds, t, m0, n0);
  else
    fused_body<false>(in, Mm, out, lds, t, m0, n0);
}

extern "C" void kernel_launch(void* const* d_in, const int* in_sizes, int n_in,
                              void* d_out, int out_size, void* d_ws, size_t ws_size,
                              hipStream_t stream) {
  const float* in   = (const float*)d_in[0];  // [4,4096,512] f32
  const float* Win  = (const float*)d_in[1];  // [512,512] f32
  const float* Wout = (const float*)d_in[2];  // [512,512] f32
  float* outp = (float*)d_out;                // [4,4096,512] f32

  u16* Mm = (u16*)d_ws;                       // 512*512 bf16

  hipLaunchKernelGGL(gemm_m,   dim3(64),  dim3(256), 0, stream, Wout, Win, Mm);
  hipLaunchKernelGGL(fused_gc, dim3(512), dim3(256), 0, stream, in, Mm, outp);
}

// Round 12
// 33.805 us; speedup vs baseline: 1.3049x; 1.3049x over previous
//
#include <hip/hip_runtime.h>
#include <hip/hip_bf16.h>

// out = conv9(in) @ M^T,  M = Wout @ Win
// R12: de-fused (R10 shape) with (1) depth-2 A prefetch in gemm_out
// (A triple-buffer, B double-buffer, vmcnt(4) steady-state) and
// (2) single-pass register-window conv (1x HBM read, no 9x L2 re-read).

typedef unsigned short u16;
typedef unsigned int u32;
typedef unsigned long long u64;
typedef __attribute__((ext_vector_type(8))) short bf16x8;
typedef __attribute__((ext_vector_type(8))) unsigned short u16x8;
typedef __attribute__((ext_vector_type(4))) float f32x4;
typedef __attribute__((ext_vector_type(2))) u32 u32x2;

typedef __attribute__((address_space(1))) const void* as1_cvp;
typedef __attribute__((address_space(3))) void* as3_vp;

#define EDIM 512
#define NROW 16384
#define CROWS 24                 // conv rows per block (2 groups x 12)
#define NCONVB 683               // ceil(16384/24)
#define GOUT 512

__device__ __forceinline__ u16 f2b(float x) {
  union { float f; u32 u; } c; c.f = x;
  return (u16)((c.u + 0x7fffu + ((c.u >> 16) & 1u)) >> 16);  // RNE
}
__device__ __forceinline__ u32 cvtpk(float lo, float hi) {
  u32 r;
  asm("v_cvt_pk_bf16_f32 %0, %1, %2" : "=v"(r) : "v"(lo), "v"(hi));
  return r;
}
__device__ __forceinline__ void async_cp16(const void* g, void* l) {
  __builtin_amdgcn_global_load_lds((as1_cvp)(u64)g, (as3_vp)(u32)(u64)l, 16, 0, 0);
}

// ---------------------------------------------------------------------------
// conv: single-pass register window. Thread: 4 cols x 12 out rows; 20-row
// fp32 window (80 VGPR). EDGE: clamp loads, mask taps at batch boundaries.
// ---------------------------------------------------------------------------
template <bool EDGE>
__device__ __forceinline__ void conv_body(const float* __restrict__ in,
                                          u16* __restrict__ Uo, int cb, int t) {
  const float G[5] = {0.39894228040143270f, 0.24197072451914337f,
                      0.053990966513188063f, 0.0044318484119380075f,
                      1.3383022576488537e-4f};
  int colv = t & 127;            // col-slot * 4
  int rgrp = t >> 7;             // 0/1
  int r0 = cb * CROWS + rgrp * 12;
  f32x4 w[20];
  if (EDGE) {
#pragma unroll
    for (int i = 0; i < 20; ++i) {
      int rr = r0 - 4 + i;
      rr = rr < 0 ? 0 : (rr > NROW - 1 ? NROW - 1 : rr);
      w[i] = *(const f32x4*)(in + (u64)rr * EDIM + colv * 4);
    }
  } else {
    const float* bp = in + (u64)(r0 - 4) * EDIM + colv * 4;
#pragma unroll
    for (int i = 0; i < 20; ++i) w[i] = *(const f32x4*)(bp + (u64)i * EDIM);
  }
#pragma unroll
  for (int j = 0; j < 12; ++j) {
    int rg = r0 + j;
    f32x4 o = {};
#pragma unroll
    for (int k = 0; k < 9; ++k) {
      float g = G[k < 4 ? 4 - k : k - 4];
      if (EDGE) g = (((rg + k - 4) >> 12) == (rg >> 12)) ? g : 0.0f;
#pragma unroll
      for (int q = 0; q < 4; ++q) o[q] += g * w[j + k][q];
    }
    if (!EDGE || rg < NROW) {
      u32x2 p;
      p[0] = cvtpk(o[0], o[1]);
      p[1] = cvtpk(o[2], o[3]);
      *(u32x2*)(Uo + (u64)rg * EDIM + colv * 4) = p;
    }
  }
}

// ---------------------------------------------------------------------------
// prep: blocks 0..63 gemm_m (M = Wout@Win, bf16); blocks 64.. conv -> Uo.
// gemm_m: 64x64 tiles, BK=128, 4 steps, raw barriers + lgkm-only waits.
// ---------------------------------------------------------------------------
__global__ __launch_bounds__(256) void prep(const float* __restrict__ in,
                                            const float* __restrict__ Win,
                                            const float* __restrict__ Wout,
                                            u16* __restrict__ Mm,
                                            u16* __restrict__ Uo) {
  __shared__ u16 plds[17408];
  int bid = (int)blockIdx.x, t = threadIdx.x;
  if (bid >= 64) {
    int cb = bid - 64;
    int c0 = cb * CROWS;
    bool edge = (((c0 - 4) >> 12) != ((c0 + CROWS + 3) >> 12));
    if (edge)
      conv_body<true>(in, Uo, cb, t);
    else
      conv_body<false>(in, Uo, cb, t);
    return;
  }
  // ---- gemm_m (R10's verified body)
  u16* la = plds;
  u16* lbt = plds + 8704;
  int w = t >> 6, l = t & 63, lr = l & 15, lk = l >> 4;
  int f0 = (bid >> 3) * 64, e0 = (bid & 7) * 64;
  int arow = t >> 2, acol = (t & 3) * 32;
  int cq = t >> 3, eo = (t & 7) * 8;
  const float* pA = Wout + (u64)(f0 + arow) * EDIM + acol;
  const float* pB = Win + (u64)(4 * cq) * EDIM + e0 + eo;
  f32x4 a8[8], b8[8];
#pragma unroll
  for (int i = 0; i < 8; ++i) a8[i] = *(const f32x4*)(pA + i * 4);
#pragma unroll
  for (int r = 0; r < 4; ++r) {
    b8[r * 2 + 0] = *(const f32x4*)(pB + r * EDIM);
    b8[r * 2 + 1] = *(const f32x4*)(pB + r * EDIM + 4);
  }
  f32x4 acc[4] = {};
  for (int kt = 0; kt < 4; ++kt) {
#pragma unroll
    for (int i = 0; i < 4; ++i) {
      u16x8 o;
#pragma unroll
      for (int q = 0; q < 4; ++q) { o[q] = f2b(a8[2 * i][q]); o[4 + q] = f2b(a8[2 * i + 1][q]); }
      *(u16x8*)(la + arow * 136 + acol + i * 8) = o;
    }
#pragma unroll
    for (int j = 0; j < 8; ++j) {
      u32x2 p;
      p[0] = cvtpk(b8[0 + (j >> 2)][j & 3], b8[2 + (j >> 2)][j & 3]);
      p[1] = cvtpk(b8[4 + (j >> 2)][j & 3], b8[6 + (j >> 2)][j & 3]);
      *(u32x2*)(lbt + (eo + j) * 136 + 4 * cq) = p;
    }
    asm volatile("s_waitcnt lgkmcnt(0)" ::: "memory");
    __builtin_amdgcn_sched_barrier(0);
    __builtin_amdgcn_s_barrier();
    if (kt < 3) {
      pA += 128; pB += (u64)128 * EDIM;
#pragma unroll
      for (int i = 0; i < 8; ++i) a8[i] = *(const f32x4*)(pA + i * 4);
#pragma unroll
      for (int r = 0; r < 4; ++r) {
        b8[r * 2 + 0] = *(const f32x4*)(pB + r * EDIM);
        b8[r * 2 + 1] = *(const f32x4*)(pB + r * EDIM + 4);
      }
    }
#pragma unroll
    for (int kk = 0; kk < 128; kk += 32) {
      bf16x8 a = *(const bf16x8*)(la + (w * 16 + lr) * 136 + kk + lk * 8);
#pragma unroll
      for (int ni = 0; ni < 4; ++ni) {
        bf16x8 bb = *(const bf16x8*)(lbt + (ni * 16 + lr) * 136 + kk + lk * 8);
        acc[ni] = __builtin_amdgcn_mfma_f32_16x16x32_bf16(a, bb, acc[ni], 0, 0, 0);
      }
    }
    asm volatile("s_waitcnt lgkmcnt(0)" ::: "memory");
    __builtin_amdgcn_sched_barrier(0);
    __builtin_amdgcn_s_barrier();
  }
#pragma unroll
  for (int ni = 0; ni < 4; ++ni)
#pragma unroll
    for (int r = 0; r < 4; ++r)
      Mm[(u64)(f0 + w * 16 + lk * 4 + r) * EDIM + e0 + ni * 16 + lr] = f2b(acc[ni][r]);
}

// ---------------------------------------------------------------------------
// gemm_out: out[16384,512] = U @ M^T, bf16 in, fp32 out. 128x128 tile, BK=64,
// 8 steps. A TRIPLE-buffered (depth-2 prefetch: each A-tile has 2 full steps
// to land), B double (L2-resident M). LDS 80KB -> 2 blocks/CU, grid 512 all
// resident. Steady-state step-top wait: queue = {A(kt)4, B(kt)4, A(kt+1)4}
// -> vmcnt(4) retires tile kt, keeps A(kt+1) in flight across the barrier.
// ---------------------------------------------------------------------------
#define ISSA(KT, BUF)                                                          \
  _Pragma("unroll") for (int i = 0; i < 4; ++i)                                \
      async_cp16(gA + (KT) * 64 + (u64)i * 32 * EDIM,                          \
                 lds + (BUF) + t * 8 + i * 2048);
#define ISSB(KT, BUF)                                                          \
  _Pragma("unroll") for (int i = 0; i < 4; ++i)                                \
      async_cp16(gB + (KT) * 64 + (u64)i * 32 * EDIM,                          \
                 lds + 24576 + (BUF) + t * 8 + i * 2048);

#define GSTEP(KT, VM)                                                          \
  {                                                                            \
    asm volatile("s_waitcnt vmcnt(" #VM ")" ::: "memory");                     \
    __builtin_amdgcn_sched_barrier(0);                                         \
    __builtin_amdgcn_s_barrier();                                              \
    if ((KT) + 1 < 8) { ISSB((KT) + 1, (((KT) + 1) & 1) * 8192) }              \
    __builtin_amdgcn_sched_barrier(0);                                         \
    if ((KT) + 2 < 8) { ISSA((KT) + 2, (((KT) + 2) % 3) * 8192) }              \
    __builtin_amdgcn_sched_barrier(0);                                         \
    const int ab = ((KT) % 3) * 8192, bb = 24576 + ((KT) & 1) * 8192;          \
    _Pragma("unroll") for (int kk = 0; kk < 64; kk += 32) {                    \
      bf16x8 af[4], bv[4];                                                     \
      _Pragma("unroll") for (int mi = 0; mi < 4; ++mi)                         \
          af[mi] = *(const bf16x8*)(lds + ab + ard[mi] +                       \
                                    ((kk + lk * 8) ^ aswz[mi]));               \
      _Pragma("unroll") for (int ni = 0; ni < 4; ++ni)                         \
          bv[ni] = *(const bf16x8*)(lds + bb + brd[ni] +                       \
                                    ((kk + lk * 8) ^ bswz[ni]));               \
      _Pragma("unroll") for (int mi = 0; mi < 4; ++mi)                         \
        _Pragma("unroll") for (int ni = 0; ni < 4; ++ni)                       \
            acc[mi][ni] = __builtin_amdgcn_mfma_f32_16x16x32_bf16(             \
                af[mi], bv[ni], acc[mi][ni], 0, 0, 0);                         \
    }                                                                          \
  }

__global__ __launch_bounds__(256, 2) void gemm_out(const u16* __restrict__ U,
                                                   const u16* __restrict__ Mm,
                                                   float* __restrict__ out) {
  __shared__ u16 lds[40960];  // A0@0 A1@8192 A2@16384 | B0@24576 B1@32768 (80KB)
  int t = threadIdx.x;
  int l = t & 63, lr = l & 15, lk = l >> 4;
  int wv = t >> 6, wr = wv >> 1, wc = wv & 1;
  int b = (int)blockIdx.x;
  int wg = (b & 7) * 64 + (b >> 3);  // bijective XCD swizzle (512 % 8 == 0)
  int m0 = (wg >> 2) * 128;
  int n0 = (wg & 3) * 128;

  int soct = (t & 7) ^ ((t >> 3) & 7);
  const u16* gA = U + (u64)(m0 + (t >> 3)) * EDIM + soct * 8;
  const u16* gB = Mm + (u64)(n0 + (t >> 3)) * EDIM + soct * 8;

  int ard[4], aswz[4], brd[4], bswz[4];
#pragma unroll
  for (int mi = 0; mi < 4; ++mi) {
    int rA = wr * 64 + mi * 16 + lr;
    ard[mi] = rA * 64; aswz[mi] = (rA & 7) << 3;
  }
#pragma unroll
  for (int ni = 0; ni < 4; ++ni) {
    int rB = wc * 64 + ni * 16 + lr;
    brd[ni] = rB * 64; bswz[ni] = (rB & 7) << 3;
  }

  f32x4 acc[4][4] = {};

  // prologue: A(0)->buf0, B(0)->B0, A(1)->buf1  (queue: A0,B0,A1)
  ISSA(0, 0)
  ISSB(0, 0)
  __builtin_amdgcn_sched_barrier(0);
  ISSA(1, 8192)
  __builtin_amdgcn_sched_barrier(0);

  GSTEP(0, 4) GSTEP(1, 4) GSTEP(2, 4) GSTEP(3, 4)
  GSTEP(4, 4) GSTEP(5, 4) GSTEP(6, 4) GSTEP(7, 0)

  // epilogue: direct fp32 stores
#pragma unroll
  for (int mi = 0; mi < 4; ++mi)
#pragma unroll
    for (int ni = 0; ni < 4; ++ni)
#pragma unroll
      for (int rr = 0; rr < 4; ++rr)
        out[(u64)(m0 + wr * 64 + mi * 16 + lk * 4 + rr) * EDIM +
            n0 + wc * 64 + ni * 16 + lr] = acc[mi][ni][rr];
}

extern "C" void kernel_launch(void* const* d_in, const int* in_sizes, int n_in,
                              void* d_out, int out_size, void* d_ws, size_t ws_size,
                              hipStream_t stream) {
  const float* in   = (const float*)d_in[0];  // [4,4096,512] f32
  const float* Win  = (const float*)d_in[1];  // [512,512] f32
  const float* Wout = (const float*)d_in[2];  // [512,512] f32
  float* outp = (float*)d_out;                // [4,4096,512] f32

  u16* Mm = (u16*)d_ws;                       // 512*512 bf16
  u16* Uo = (u16*)d_ws + (u64)EDIM * EDIM;    // 16384*512 bf16

  hipLaunchKernelGGL(prep,     dim3(64 + NCONVB), dim3(256), 0, stream, in, Win, Wout, Mm, Uo);
  hipLaunchKernelGGL(gemm_out, dim3(GOUT),        dim3(256), 0, stream, Uo, Mm, outp);
}